// Round 2
// baseline (1489.407 us; speedup 1.0000x reference)
//
#include <hip/hip_runtime.h>
#include <math.h>

// MoE gate: logits = X[T,4096] @ W^T[4096,64]; softmax over 64; top-2.
// Output layout (float32): [T*2] indices-as-float, then [T*2] weights.
//
// R3 = R2 with the LDS stride bug fixed: a row is 64 floats = 256 B (<<8),
// R2 used <<10 which ran off the end of the chunk buffer (absmax 63, garbage
// indices). Swizzle algebra re-verified: write phys_slot = slot ^ (row&15),
// read at slot (lane&15)^g recovers logical slot g for row==lane; slot bits
// are bits 4..7, row bits start at bit 8 -> no carry.
//
// Design (R2): lane=token, wave=expert-group.
//   - 512 threads = 8 waves, 64 tokens/block, 8 experts/wave, acc[8]/thread.
//   - W read via SCALAR pipe: wave-uniform address -> s_load from L2-hot W
//     (1 MiB). No LDS, no VALU for W fetch.
//   - X chunk [64 tok][64 k] in LDS, reg-staged (coalesced global + ds_write,
//     NOT global_load_lds so SMEM scalarization of W isn't blocked),
//     double-buffered, write-side XOR swizzle (2-way reads, free per m136).
//   - T14 split: issue next-chunk loads early, ds_write late, 1 barrier/chunk.
// Target: fp32-VALU-bound ~130-170 us (8.6 G FMA = 109 us at 100% VALU).

#define BK 64
#define NCHUNK (4096 / BK)

__global__ __launch_bounds__(512, 4)
void moe_gate(const float* __restrict__ X, const float* __restrict__ W,
              float* __restrict__ out, int T) {
  __shared__ float4 sx[2][1024];     // double-buffered X chunk, 2 x 16 KB
  __shared__ float slog[64 * 65];    // epilogue logits, padded

  const int t    = threadIdx.x;
  const int lane = t & 63;                                        // token
  const int e0   = __builtin_amdgcn_readfirstlane((t >> 6) << 3); // expert base

  const long tok0 = (long)blockIdx.x * 64;

  // --- staging map: thread t stages rows {t>>4, 32+(t>>4)}, float4 slot t&15
  const int srow0 = t >> 4;          // 0..31
  const int srow1 = srow0 + 32;      // 32..63
  const int sslot = t & 15;
  const float* xsA = X + (tok0 + srow0) * 4096 + (sslot << 2);
  const float* xsB = X + (tok0 + srow1) * 4096 + (sslot << 2);
  // LDS byte offsets: row stride 256 B, swizzle phys_slot = slot ^ (row & 15)
  const int dA = (srow0 << 8) + ((sslot ^ (srow0 & 15)) << 4);
  const int dB = (srow1 << 8) + ((sslot ^ (srow1 & 15)) << 4);

  // --- compute-side read base (byte offset); xv[g] at xoff ^ (g<<4)
  const int xoff = (lane << 8) + ((lane & 15) << 4);

  float acc[8];
  #pragma unroll
  for (int j = 0; j < 8; ++j) acc[j] = 0.f;

  // prologue: stage chunk 0 into buffer 0
  {
    float4 a = *(const float4*)xsA;
    float4 b = *(const float4*)xsB;
    *(float4*)((char*)(&sx[0][0]) + dA) = a;
    *(float4*)((char*)(&sx[0][0]) + dB) = b;
  }
  __syncthreads();

  for (int c = 0; c < NCHUNK; ++c) {
    const int k0 = c * BK;
    const char* xb = (const char*)(&sx[c & 1][0]);

    // issue next-chunk global loads early (latency hides under compute)
    float4 nA, nB;
    if (c + 1 < NCHUNK) {
      nA = *(const float4*)(xsA + k0 + BK);
      nB = *(const float4*)(xsB + k0 + BK);
    }

    // this lane's token row for this chunk: 16 x float4 (swizzled ds_read_b128)
    float4 xv[16];
    #pragma unroll
    for (int g = 0; g < 16; ++g)
      xv[g] = *(const float4*)(xb + (xoff ^ (g << 4)));

    // 8 experts; W row is wave-uniform -> scalar loads feeding v_fma s-operand
    #pragma unroll
    for (int j = 0; j < 8; ++j) {
      const float4* wq = (const float4*)(W + (long)(e0 + j) * 4096 + k0);
      float c0 = 0.f, c1 = 0.f, c2 = 0.f, c3 = 0.f;   // chunk-local partials
      #pragma unroll
      for (int g = 0; g < 16; ++g) {
        const float4 wv = wq[g];
        c0 = fmaf(xv[g].x, wv.x, c0);
        c1 = fmaf(xv[g].y, wv.y, c1);
        c2 = fmaf(xv[g].z, wv.z, c2);
        c3 = fmaf(xv[g].w, wv.w, c3);
      }
      acc[j] += (c0 + c1) + (c2 + c3);   // bounded error, matches R1 kernel
    }

    // write next chunk into the other buffer (after compute, T14 late-write)
    if (c + 1 < NCHUNK) {
      char* xn = (char*)(&sx[(c + 1) & 1][0]);
      *(float4*)(xn + dA) = nA;
      *(float4*)(xn + dB) = nB;
    }
    __syncthreads();   // single barrier per chunk
  }

  // --- epilogue: logits -> LDS [64][65], then 1 thread per token ---
  #pragma unroll
  for (int j = 0; j < 8; ++j)
    slog[lane * 65 + e0 + j] = acc[j];
  __syncthreads();

  if (t < 64) {
    const float* row = slog + t * 65;
    // top-2 on logits; strict '>' = lowest-index-first on ties (jax.lax.top_k)
    float b1 = -1e30f, b2 = -1e30f;
    int i1 = 0, i2 = 0;
    for (int e = 0; e < 64; ++e) {
      const float v = row[e];
      if (v > b1)      { b2 = b1; i2 = i1; b1 = v; i1 = e; }
      else if (v > b2) { b2 = v; i2 = e; }
    }
    float s = 0.f;
    for (int e = 0; e < 64; ++e) s += expf(row[e] - b1);
    const float inv = 1.0f / s;
    const long gt = tok0 + t;
    out[gt * 2 + 0] = (float)i1;
    out[gt * 2 + 1] = (float)i2;
    float* ow = out + (long)T * 2;
    ow[gt * 2 + 0] = inv;                 // exp(b1-b1)/s
    ow[gt * 2 + 1] = expf(b2 - b1) * inv;
  }
}

extern "C" void kernel_launch(void* const* d_in, const int* in_sizes, int n_in,
                              void* d_out, int out_size, void* d_ws, size_t ws_size,
                              hipStream_t stream) {
  const float* X = (const float*)d_in[0];   // [4,8192,4096] fp32
  const float* W = (const float*)d_in[1];   // [64,4096] fp32
  float* out = (float*)d_out;               // [T*2] idx-as-float, [T*2] weights
  const int T = in_sizes[0] / 4096;         // 32768 tokens
  const int grid = T / 64;                  // 512 workgroups
  hipLaunchKernelGGL(moe_gate, dim3(grid), dim3(512), 0, stream, X, W, out, T);
}

// Round 3
// 1166.190 us; speedup vs baseline: 1.2772x; 1.2772x over previous
//
#include <hip/hip_runtime.h>
#include <math.h>

// MoE gate: logits = X[T,4096] @ W^T[4096,64]; softmax over 64; top-2.
// Output layout (float32): [T*2] indices-as-float, then [T*2] weights.
//
// R4 = R3 with the register-pressure fix. R3 passed but spilled: xv[16]
// (64 floats) live across the 8-expert loop overflowed the 64-VGPR
// allocation -> scratch traffic (WRITE_SIZE 512 KB -> 152 MB, dur 1020 us,
// 80% of VALU issue was spill overhead). Design (lane=token, wave=expert-
// group, W on the scalar pipe, swizzled X in LDS, 0 bank conflicts) was
// verified correct — only the schedule was broken.
//
// Fix:
//   - K=64 chunk split into 4 sub-blocks (gg) of 4 float4s; '#pragma
//     unroll 1' on gg prevents the scheduler from re-hoisting all 16
//     ds_read_b128 (live X window = 4 float4 = 16 VGPR). ~58 VGPR total.
//   - Per-(gg,j) 2-deep dot partials d0/d1, per-chunk partial cp[j],
//     kernel-long acc[j]: same error class as R3 (short FMA chains,
//     64-length top chain) — R3 passed absmax 9.8e-4 vs thr 1.26.
//   - Epilogue logits overlay sx (union) -> LDS 49.6 KB -> 32 KB ->
//     4 blocks/CU (32 waves, 100% occupancy at <=64 VGPR).
// Target: fp32-VALU-bound. 8.6 G wave-FMAs = 109 us at 100% VALU issue;
// ~15% non-FMA VALU (xor/adds/staging) -> predict 150-190 us.

#define BK 64
#define NCHUNK (4096 / BK)

__global__ __launch_bounds__(512, 4)
void moe_gate(const float* __restrict__ X, const float* __restrict__ W,
              float* __restrict__ out, int T) {
  __shared__ float4 sx[2][1024];     // 2 x 16 KB X chunks; epilogue overlays
  float* slog = (float*)sx;          // [64][65] logits, reused after main loop

  const int t    = threadIdx.x;
  const int lane = t & 63;                                        // token
  const int e0   = __builtin_amdgcn_readfirstlane((t >> 6) << 3); // expert base
  const long tok0 = (long)blockIdx.x * 64;

  // --- staging map: thread t stages rows {t>>4, 32+(t>>4)}, float4 slot t&15
  const int srow0 = t >> 4;          // 0..31
  const int srow1 = srow0 + 32;      // 32..63
  const int sslot = t & 15;
  const float* xsA = X + (tok0 + srow0) * 4096 + (sslot << 2);
  const float* xsB = X + (tok0 + srow1) * 4096 + (sslot << 2);
  // LDS byte offsets: row stride 256 B, swizzle phys_slot = slot ^ (row & 15)
  const int dA = (srow0 << 8) + ((sslot ^ (srow0 & 15)) << 4);
  const int dB = (srow1 << 8) + ((sslot ^ (srow1 & 15)) << 4);

  // --- compute-side read base (byte offset); logical slot g at xoff ^ (g<<4)
  const int xoff = (lane << 8) + ((lane & 15) << 4);

  float acc[8];
  #pragma unroll
  for (int j = 0; j < 8; ++j) acc[j] = 0.f;

  // prologue: stage chunk 0 into buffer 0
  {
    float4 a = *(const float4*)xsA;
    float4 b = *(const float4*)xsB;
    *(float4*)((char*)sx + dA) = a;
    *(float4*)((char*)sx + dB) = b;
  }
  __syncthreads();

  for (int c = 0; c < NCHUNK; ++c) {
    const int k0 = c * BK;
    const char* xb = (const char*)(&sx[c & 1][0]);

    // issue next-chunk global loads early (latency hides under compute)
    float4 nA, nB;
    if (c + 1 < NCHUNK) {
      nA = *(const float4*)(xsA + k0 + BK);
      nB = *(const float4*)(xsB + k0 + BK);
    }

    float cp[8];
    #pragma unroll
    for (int j = 0; j < 8; ++j) cp[j] = 0.f;

    // 4 sub-blocks of K=16; unroll 1 caps the live X window at 4 float4s
    // (R3's spill cause was all 16 live at once under a 64-VGPR budget).
    #pragma unroll 1
    for (int gg = 0; gg < 4; ++gg) {
      float4 xv[4];
      #pragma unroll
      for (int g2 = 0; g2 < 4; ++g2)
        xv[g2] = *(const float4*)(xb + (xoff ^ ((gg * 4 + g2) << 4)));

      #pragma unroll
      for (int j = 0; j < 8; ++j) {
        // W row address is wave-uniform -> scalar (s_load) path, no LDS/VALU
        const float4* wq =
            (const float4*)(W + (long)(e0 + j) * 4096 + k0) + gg * 4;
        float d0 = 0.f, d1 = 0.f;
        #pragma unroll
        for (int g2 = 0; g2 < 4; ++g2) {
          const float4 wv = wq[g2];
          d0 = fmaf(xv[g2].x, wv.x, d0);
          d1 = fmaf(xv[g2].y, wv.y, d1);
          d0 = fmaf(xv[g2].z, wv.z, d0);
          d1 = fmaf(xv[g2].w, wv.w, d1);
        }
        cp[j] += d0 + d1;
      }
    }
    #pragma unroll
    for (int j = 0; j < 8; ++j) acc[j] += cp[j];

    // write next chunk into the other buffer (after compute, T14 late-write)
    if (c + 1 < NCHUNK) {
      char* xn = (char*)(&sx[(c + 1) & 1][0]);
      *(float4*)(xn + dA) = nA;
      *(float4*)(xn + dB) = nB;
    }
    __syncthreads();   // single barrier per chunk
  }

  // --- epilogue: logits -> LDS [64][65] (overlaying sx), 1 thread/token ---
  #pragma unroll
  for (int j = 0; j < 8; ++j)
    slog[lane * 65 + e0 + j] = acc[j];
  __syncthreads();

  if (t < 64) {
    const float* row = slog + t * 65;
    // top-2 on logits; strict '>' = lowest-index-first on ties (jax.lax.top_k)
    float b1 = -1e30f, b2 = -1e30f;
    int i1 = 0, i2 = 0;
    for (int e = 0; e < 64; ++e) {
      const float v = row[e];
      if (v > b1)      { b2 = b1; i2 = i1; b1 = v; i1 = e; }
      else if (v > b2) { b2 = v; i2 = e; }
    }
    float s = 0.f;
    for (int e = 0; e < 64; ++e) s += expf(row[e] - b1);
    const float inv = 1.0f / s;
    const long gt = tok0 + t;
    out[gt * 2 + 0] = (float)i1;
    out[gt * 2 + 1] = (float)i2;
    float* ow = out + (long)T * 2;
    ow[gt * 2 + 0] = inv;                 // exp(b1-b1)/s
    ow[gt * 2 + 1] = expf(b2 - b1) * inv;
  }
}

extern "C" void kernel_launch(void* const* d_in, const int* in_sizes, int n_in,
                              void* d_out, int out_size, void* d_ws, size_t ws_size,
                              hipStream_t stream) {
  const float* X = (const float*)d_in[0];   // [4,8192,4096] fp32
  const float* W = (const float*)d_in[1];   // [64,4096] fp32
  float* out = (float*)d_out;               // [T*2] idx-as-float, [T*2] weights
  const int T = in_sizes[0] / 4096;         // 32768 tokens
  const int grid = T / 64;                  // 512 workgroups
  hipLaunchKernelGGL(moe_gate, dim3(grid), dim3(512), 0, stream, X, W, out, T);
}